// Round 1
// baseline (182.017 us; speedup 1.0000x reference)
//
#include <hip/hip_runtime.h>

// Problem constants (match reference)
#define NB 8
#define HH 352
#define WW 352
#define RAD 5
#define TX 32
#define TY 32
#define LW 42        // tile width  with halo (TX + 2*RAD)
#define LH 42        // tile height with halo
#define LSTRIDE 43   // padded row stride in float4 units (odd -> spread banks)

// exp(-200*s): use fast v_exp_f32 path
#define NEG_ALPHA (-200.0f)

__global__ __launch_bounds__(256, 2)
void btm_loss_kernel(const float* __restrict__ pred,
                     const float* __restrict__ feat,
                     float* __restrict__ ws) {
    __shared__ float4 tile[LH * LSTRIDE];  // 42*43*16B = 28.9 KB

    const int tiles_x = WW / TX;  // 11
    const int tiles_y = HH / TY;  // 11
    int bid = blockIdx.x;
    int tx_blk = bid % tiles_x;
    int ty_blk = (bid / tiles_x) % tiles_y;
    int n = bid / (tiles_x * tiles_y);

    const int x0 = tx_blk * TX;
    const int y0 = ty_blk * TY;

    const size_t plane = (size_t)HH * WW;
    const float* fr = feat + ((size_t)n * 3 + 0) * plane;
    const float* fg = feat + ((size_t)n * 3 + 1) * plane;
    const float* fb = feat + ((size_t)n * 3 + 2) * plane;
    const float* ps = pred + (size_t)n * plane;

    // ---- stage tile (zero-padded halo, matching jnp.pad) ----
    for (int i = threadIdx.x; i < LH * LW; i += 256) {
        int lr = i / LW;
        int lc = i - lr * LW;
        int gy = y0 + lr - RAD;
        int gx = x0 + lc - RAD;
        float4 v = make_float4(0.f, 0.f, 0.f, 0.f);
        if ((unsigned)gy < (unsigned)HH && (unsigned)gx < (unsigned)WW) {
            int gi = gy * WW + gx;
            v.x = fr[gi];
            v.y = fg[gi];
            v.z = fb[gi];
            v.w = ps[gi];
        }
        tile[lr * LSTRIDE + lc] = v;
    }
    __syncthreads();

    const int t   = threadIdx.x;
    const int txq = t & 7;    // 0..7  (x group)
    const int ty  = t >> 3;   // 0..31 (row)
    const int px0 = txq * 4;  // local x of first of 4 pixels

    // centers for the 4 pixels this thread owns
    float4 c0 = tile[(ty + RAD) * LSTRIDE + (px0 + 0 + RAD)];
    float4 c1 = tile[(ty + RAD) * LSTRIDE + (px0 + 1 + RAD)];
    float4 c2 = tile[(ty + RAD) * LSTRIDE + (px0 + 2 + RAD)];
    float4 c3 = tile[(ty + RAD) * LSTRIDE + (px0 + 3 + RAD)];

    float acc0 = 0.f, acc1 = 0.f, acc2 = 0.f, acc3 = 0.f;

    // ---- 11x11 bilateral accumulation, register-rolled over x ----
    for (int dy = 0; dy < 11; ++dy) {
        const float4* row = &tile[(ty + dy) * LSTRIDE + px0];
        float4 wv[14];
        #pragma unroll
        for (int j = 0; j < 14; ++j) wv[j] = row[j];

        #pragma unroll
        for (int dx = 0; dx < 11; ++dx) {
            // pixel 0
            {
                float4 wn = wv[dx + 0];
                float d0 = wn.x - c0.x, d1 = wn.y - c0.y, d2 = wn.z - c0.z;
                float s = fmaf(d0, d0, fmaf(d1, d1, d2 * d2));
                float wgt = __expf(NEG_ALPHA * s);
                acc0 = fmaf(wgt, fabsf(wn.w - c0.w), acc0);
            }
            // pixel 1
            {
                float4 wn = wv[dx + 1];
                float d0 = wn.x - c1.x, d1 = wn.y - c1.y, d2 = wn.z - c1.z;
                float s = fmaf(d0, d0, fmaf(d1, d1, d2 * d2));
                float wgt = __expf(NEG_ALPHA * s);
                acc1 = fmaf(wgt, fabsf(wn.w - c1.w), acc1);
            }
            // pixel 2
            {
                float4 wn = wv[dx + 2];
                float d0 = wn.x - c2.x, d1 = wn.y - c2.y, d2 = wn.z - c2.z;
                float s = fmaf(d0, d0, fmaf(d1, d1, d2 * d2));
                float wgt = __expf(NEG_ALPHA * s);
                acc2 = fmaf(wgt, fabsf(wn.w - c2.w), acc2);
            }
            // pixel 3
            {
                float4 wn = wv[dx + 3];
                float d0 = wn.x - c3.x, d1 = wn.y - c3.y, d2 = wn.z - c3.z;
                float s = fmaf(d0, d0, fmaf(d1, d1, d2 * d2));
                float wgt = __expf(NEG_ALPHA * s);
                acc3 = fmaf(wgt, fabsf(wn.w - c3.w), acc3);
            }
        }
    }

    // ---- mask (dil - ero of 5x5 maxpool on lbl; OOB taps excluded) ----
    const int gy = y0 + ty;
    float num = 0.f, den = 0.f;
    float accs[4] = {acc0, acc1, acc2, acc3};
    #pragma unroll
    for (int k = 0; k < 4; ++k) {
        int px = px0 + k;
        int gx = x0 + px;
        float mn = 1.f, mx = 0.f;
        #pragma unroll
        for (int dy2 = -2; dy2 <= 2; ++dy2) {
            bool rowv = (unsigned)(gy + dy2) < (unsigned)HH;
            #pragma unroll
            for (int dx2 = -2; dx2 <= 2; ++dx2) {
                float sal = tile[(ty + RAD + dy2) * LSTRIDE + (px + RAD + dx2)].w;
                float l = (sal > 0.5f) ? 1.f : 0.f;
                bool valid = rowv && ((unsigned)(gx + dx2) < (unsigned)WW);
                mx = fmaxf(mx, l);                 // OOB LDS sal==0 -> l==0: neutral for max
                mn = fminf(mn, valid ? l : 1.f);   // OOB excluded from min
            }
        }
        float mask = mx - mn;  // 0 or 1
        num = fmaf(mask, accs[k], num);
        den += mask;
    }

    // ---- wave (64-lane) reduction, one atomic per wave ----
    #pragma unroll
    for (int off = 32; off > 0; off >>= 1) {
        num += __shfl_down(num, off, 64);
        den += __shfl_down(den, off, 64);
    }
    if ((t & 63) == 0) {
        atomicAdd(&ws[0], num);
        atomicAdd(&ws[1], den);
    }
}

__global__ void btm_finalize_kernel(const float* __restrict__ ws,
                                    float* __restrict__ out) {
    out[0] = ws[0] / (ws[1] + 1e-6f);
}

extern "C" void kernel_launch(void* const* d_in, const int* in_sizes, int n_in,
                              void* d_out, int out_size, void* d_ws, size_t ws_size,
                              hipStream_t stream) {
    const float* pred = (const float*)d_in[0];  // (8,1,352,352) fp32
    const float* feat = (const float*)d_in[1];  // (8,3,352,352) fp32
    float* out = (float*)d_out;                 // scalar fp32
    float* ws  = (float*)d_ws;

    // ws is poisoned to 0xAA before every call -> zero the 2 accumulators
    hipMemsetAsync(d_ws, 0, 2 * sizeof(float), stream);

    const int tiles = (WW / TX) * (HH / TY) * NB;  // 11*11*8 = 968
    btm_loss_kernel<<<dim3(tiles), dim3(256), 0, stream>>>(pred, feat, ws);
    btm_finalize_kernel<<<dim3(1), dim3(1), 0, stream>>>(ws, out);
}

// Round 2
// 127.128 us; speedup vs baseline: 1.4318x; 1.4318x over previous
//
#include <hip/hip_runtime.h>

// Problem constants (match reference)
#define NB 8
#define HH 352
#define WW 352
#define RAD 5
#define TX 32
#define TY 16
#define LW (TX + 2*RAD)     // 42
#define LH (TY + 2*RAD)     // 26
#define LSTRIDE 43          // padded row stride in float4 units (odd -> spread banks)
#define TILES_X (WW / TX)   // 11
#define TILES_Y (HH / TY)   // 22
#define NBLK (TILES_X * TILES_Y * NB)  // 1936

// Pre-scale rgb by sqrt(ALPHA * log2(e)) so wgt = exp2(-sum(d^2)) — saves a
// per-tap multiply and lets v_exp_f32 take the negate as an input modifier.
// sqrt(200 * 1.4426950408889634) = sqrt(288.53900817779268)
#define RGB_SCALE 16.98644781888824f

__global__ __launch_bounds__(256, 6)
void btm_loss_kernel(const float* __restrict__ pred,
                     const float* __restrict__ feat,
                     float2* __restrict__ partials) {
    __shared__ float4 tile[LH * LSTRIDE];  // 26*43*16B = 17.9 KB
    __shared__ float2 wred[4];

    int bid = blockIdx.x;
    int tx_blk = bid % TILES_X;
    int ty_blk = (bid / TILES_X) % TILES_Y;
    int n = bid / (TILES_X * TILES_Y);

    const int x0 = tx_blk * TX;
    const int y0 = ty_blk * TY;

    const size_t plane = (size_t)HH * WW;
    const float* fr = feat + ((size_t)n * 3 + 0) * plane;
    const float* fg = feat + ((size_t)n * 3 + 1) * plane;
    const float* fb = feat + ((size_t)n * 3 + 2) * plane;
    const float* ps = pred + (size_t)n * plane;

    // ---- stage tile (zero-padded halo, matching jnp.pad; rgb pre-scaled) ----
    for (int i = threadIdx.x; i < LH * LW; i += 256) {
        int lr = i / LW;
        int lc = i - lr * LW;
        int gy = y0 + lr - RAD;
        int gx = x0 + lc - RAD;
        float4 v = make_float4(0.f, 0.f, 0.f, 0.f);
        if ((unsigned)gy < (unsigned)HH && (unsigned)gx < (unsigned)WW) {
            int gi = gy * WW + gx;
            v.x = fr[gi] * RGB_SCALE;
            v.y = fg[gi] * RGB_SCALE;
            v.z = fb[gi] * RGB_SCALE;
            v.w = ps[gi];
        }
        tile[lr * LSTRIDE + lc] = v;
    }
    __syncthreads();

    const int t   = threadIdx.x;
    const int txq = t & 15;   // 0..15 (x group)
    const int ty  = t >> 4;   // 0..15 (row)
    const int px0 = txq * 2;  // local x of first of 2 pixels

    float4 c0 = tile[(ty + RAD) * LSTRIDE + (px0 + 0 + RAD)];
    float4 c1 = tile[(ty + RAD) * LSTRIDE + (px0 + 1 + RAD)];

    float acc0 = 0.f, acc1 = 0.f;

    // ---- 11x11 bilateral accumulation, register-rolled over x ----
    for (int dy = 0; dy < 11; ++dy) {
        const float4* row = &tile[(ty + dy) * LSTRIDE + px0];
        float4 wv[12];
        #pragma unroll
        for (int j = 0; j < 12; ++j) wv[j] = row[j];

        #pragma unroll
        for (int dx = 0; dx < 11; ++dx) {
            {
                float4 wn = wv[dx + 0];
                float d0 = wn.x - c0.x, d1 = wn.y - c0.y, d2 = wn.z - c0.z;
                float s = fmaf(d0, d0, fmaf(d1, d1, d2 * d2));
                acc0 = fmaf(exp2f(-s), fabsf(wn.w - c0.w), acc0);
            }
            {
                float4 wn = wv[dx + 1];
                float d0 = wn.x - c1.x, d1 = wn.y - c1.y, d2 = wn.z - c1.z;
                float s = fmaf(d0, d0, fmaf(d1, d1, d2 * d2));
                acc1 = fmaf(exp2f(-s), fabsf(wn.w - c1.w), acc1);
            }
        }
    }

    // ---- mask (dil - ero of 5x5 maxpool on lbl; OOB taps excluded) ----
    const int gy = y0 + ty;
    float num = 0.f, den = 0.f;
    float accs[2] = {acc0, acc1};
    #pragma unroll
    for (int k = 0; k < 2; ++k) {
        int px = px0 + k;
        int gx = x0 + px;
        float mn = 1.f, mx = 0.f;
        #pragma unroll
        for (int dy2 = -2; dy2 <= 2; ++dy2) {
            bool rowv = (unsigned)(gy + dy2) < (unsigned)HH;
            #pragma unroll
            for (int dx2 = -2; dx2 <= 2; ++dx2) {
                float sal = tile[(ty + RAD + dy2) * LSTRIDE + (px + RAD + dx2)].w;
                float l = (sal > 0.5f) ? 1.f : 0.f;
                bool valid = rowv && ((unsigned)(gx + dx2) < (unsigned)WW);
                mx = fmaxf(mx, l);                 // OOB LDS sal==0 -> l==0: neutral for max
                mn = fminf(mn, valid ? l : 1.f);   // OOB excluded from min
            }
        }
        float mask = mx - mn;  // 0 or 1
        num = fmaf(mask, accs[k], num);
        den += mask;
    }

    // ---- wave reduce, then block reduce, then one partial store per block ----
    #pragma unroll
    for (int off = 32; off > 0; off >>= 1) {
        num += __shfl_down(num, off, 64);
        den += __shfl_down(den, off, 64);
    }
    int wid  = t >> 6;
    int lane = t & 63;
    if (lane == 0) wred[wid] = make_float2(num, den);
    __syncthreads();
    if (t == 0) {
        float2 a = wred[0];
        #pragma unroll
        for (int w = 1; w < 4; ++w) { a.x += wred[w].x; a.y += wred[w].y; }
        partials[bid] = a;  // deterministic, no memset/atomics needed
    }
}

__global__ __launch_bounds__(256)
void btm_finalize_kernel(const float2* __restrict__ partials,
                         float* __restrict__ out) {
    __shared__ float2 wred[4];
    float num = 0.f, den = 0.f;
    for (int i = threadIdx.x; i < NBLK; i += 256) {
        float2 p = partials[i];
        num += p.x;
        den += p.y;
    }
    #pragma unroll
    for (int off = 32; off > 0; off >>= 1) {
        num += __shfl_down(num, off, 64);
        den += __shfl_down(den, off, 64);
    }
    int wid  = threadIdx.x >> 6;
    int lane = threadIdx.x & 63;
    if (lane == 0) wred[wid] = make_float2(num, den);
    __syncthreads();
    if (threadIdx.x == 0) {
        float2 a = wred[0];
        #pragma unroll
        for (int w = 1; w < 4; ++w) { a.x += wred[w].x; a.y += wred[w].y; }
        out[0] = a.x / (a.y + 1e-6f);
    }
}

extern "C" void kernel_launch(void* const* d_in, const int* in_sizes, int n_in,
                              void* d_out, int out_size, void* d_ws, size_t ws_size,
                              hipStream_t stream) {
    const float* pred = (const float*)d_in[0];  // (8,1,352,352) fp32
    const float* feat = (const float*)d_in[1];  // (8,3,352,352) fp32
    float* out = (float*)d_out;                 // scalar fp32
    float2* partials = (float2*)d_ws;           // NBLK float2 = 15.5 KB

    btm_loss_kernel<<<dim3(NBLK), dim3(256), 0, stream>>>(pred, feat, partials);
    btm_finalize_kernel<<<dim3(1), dim3(256), 0, stream>>>(partials, out);
}